// Round 2
// baseline (325.402 us; speedup 1.0000x reference)
//
#include <hip/hip_runtime.h>
#include <hip/hip_fp16.h>

// VGAE on GCN: N=50000, E=1.6M, IN=256, HIDDEN=128, OUT=64.
// Round 12b: quarter-split gather — feature tables stored [4][N][32] f16 so each
// 3.2MB quarter fits a per-XCD 4MiB L2; gather runs 4 quarter-passes (quarter =
// slow blockIdx dim -> concurrent blocks share one resident quarter).
// dinv[src] is folded into table rows at the GEMM epilogue, so the per-edge
// inner loop is a pure f16 add (no dependent dinv gather); final scale by
// dinv[dst] once per node. Wave = 16 edge-slots x 4 lanes x 16B.
// (12b: nontemporal stores use ext_vector f32x4 — HIP float4 class rejected.)

#define IN_DIM 256
#define F1 128   // HIDDEN
#define F2 64    // OUT
#define QF 32    // features per quarter (F1/4)
#define BN 128        // nodes per bucket
#define CAP 4736      // bucket capacity: mean 4096, +10 sigma
#define BIN_EDGES 4096  // edges per binning block (512 thr x 8)

typedef _Float16 f16x8 __attribute__((ext_vector_type(8)));
typedef float f32x4 __attribute__((ext_vector_type(4)));

static inline int cdiv_i(int a, int b) { return (a + b - 1) / b; }

// ---- weight prep: fragment-ordered fp16 buffers ----
__global__ void k_prep_frags(const float* __restrict__ W1,
                             const float* __restrict__ Wmu,
                             const float* __restrict__ Wls,
                             __half* __restrict__ W1frag,
                             __half* __restrict__ Wcfrag) {
    int t = blockIdx.x * blockDim.x + threadIdx.x;
    if (t < 8 * 8 * 64) {
        int lane = t & 63, nt = (t >> 6) & 7, ks = t >> 9;
        int k0 = ks * 32 + ((lane >> 4) << 3);
        int n = nt * 16 + (lane & 15);
#pragma unroll
        for (int j = 0; j < 8; ++j)
            W1frag[(size_t)t * 8 + j] = __float2half(W1[(k0 + j) * F1 + n]);
    } else if (t < 8 * 8 * 64 + 4 * 8 * 64) {
        int u = t - 8 * 8 * 64;
        int lane = u & 63, nt = (u >> 6) & 7, ks = u >> 9;
        int k0 = ks * 32 + ((lane >> 4) << 3);
        int c = nt * 16 + (lane & 15);
        const float* W = (c < F2) ? (Wmu + c) : (Wls + (c - F2));
#pragma unroll
        for (int j = 0; j < 8; ++j)
            Wcfrag[(size_t)u * 8 + j] = __float2half(W[(k0 + j) * F2]);
    }
}

// ---- pass 1: bin edges by dst>>7; packed pair = (dst&127)<<16 | src ----
__global__ __launch_bounds__(512) void k_binning(const int* __restrict__ src,
                                                 const int* __restrict__ dst,
                                                 int* __restrict__ bcur,
                                                 int* __restrict__ pairs, int E) {
    __shared__ int hcnt[512];
    __shared__ int hrank[512];
    __shared__ int hbase[512];
    __shared__ int lbase[512];
    __shared__ int stage[BIN_EDGES];
    __shared__ int gaddr[BIN_EDGES];
    const int tid = threadIdx.x;
    hcnt[tid] = 0; hrank[tid] = 0;
    __syncthreads();
    const int e0 = blockIdx.x * BIN_EDGES;
    int s_[8], d_[8];
#pragma unroll
    for (int it = 0; it < 8; ++it) {
        int e = e0 + it * 512 + tid;
        if (e < E) {
            s_[it] = src[e];
            d_[it] = dst[e];
            atomicAdd(&hcnt[d_[it] >> 7], 1);
        } else {
            d_[it] = -1;
        }
    }
    __syncthreads();
    int v = hcnt[tid];
    lbase[tid] = v;
    __syncthreads();
    for (int ofs = 1; ofs < 512; ofs <<= 1) {
        int add = (tid >= ofs) ? lbase[tid - ofs] : 0;
        __syncthreads();
        lbase[tid] += add;
        __syncthreads();
    }
    int total = lbase[511];
    int excl = lbase[tid] - v;
    __syncthreads();
    lbase[tid] = excl;
    hbase[tid] = v ? atomicAdd(&bcur[tid], v) : 0;
    __syncthreads();
#pragma unroll
    for (int it = 0; it < 8; ++it) {
        if (d_[it] >= 0) {
            int b = d_[it] >> 7;
            int r = atomicAdd(&hrank[b], 1);
            int li = lbase[b] + r;
            stage[li] = ((d_[it] & (BN - 1)) << 16) | s_[it];
            gaddr[li] = b * CAP + hbase[b] + r;
        }
    }
    __syncthreads();
    for (int i = tid; i < total; i += 512)
        pairs[gaddr[i]] = stage[i];
}

// ---- pass 2: per-bucket histogram -> scan -> dinv + [rs,re) + staged ssrc ----
__global__ __launch_bounds__(512) void k_bucket_build(const int* __restrict__ pairs,
                                                      const int* __restrict__ bcur,
                                                      float* __restrict__ dinv,
                                                      int* __restrict__ rs,
                                                      int* __restrict__ re,
                                                      int* __restrict__ ssrc, int N) {
    __shared__ int hist[BN];
    __shared__ int offs[BN];
    __shared__ int stage[CAP];
    const int b = blockIdx.x;
    const int n0 = b * BN;
    const int tid = threadIdx.x;
    const int pbase = b * CAP;
    const int cnt = min(bcur[b], CAP);
    if (tid < BN) hist[tid] = 0;
    __syncthreads();
    for (int e = tid; e < cnt; e += 512)
        atomicAdd(&hist[pairs[pbase + e] >> 16], 1);
    __syncthreads();
    if (tid < BN) offs[tid] = hist[tid];
    __syncthreads();
    for (int ofs = 1; ofs < BN; ofs <<= 1) {
        int add = 0;
        if (tid < BN && tid >= ofs) add = offs[tid - ofs];
        __syncthreads();
        if (tid < BN) offs[tid] += add;
        __syncthreads();
    }
    if (tid < BN) {
        int incl = offs[tid];
        int excl = incl - hist[tid];
        int n = n0 + tid;
        if (n < N) {
            dinv[n] = rsqrtf((float)hist[tid] + 1.0f);   // +1 self-loop
            rs[n] = pbase + excl;
            re[n] = pbase + incl;
        }
        offs[tid] = excl;
    }
    __syncthreads();
    for (int e = tid; e < cnt; e += 512) {
        int p = pairs[pbase + e];
        int idx = atomicAdd(&offs[p >> 16], 1);
        stage[idx] = p & 0xFFFF;
    }
    __syncthreads();
    for (int i = tid; i < cnt; i += 512) ssrc[pbase + i] = stage[i];
}

// ---- GEMM1 MFMA: tq[4][M][32] = fp16( dinv[m] * (x[M,256] @ W1)[m] ) ----
__global__ __launch_bounds__(256) void k_gemm1_mfma(const float* __restrict__ x,
                                                    const __half* __restrict__ W1frag,
                                                    const float* __restrict__ dinv,
                                                    __half* __restrict__ C, int M) {
    const int wave = threadIdx.x >> 6;
    const int lane = threadIdx.x & 63;
    const int m0 = blockIdx.x * 64 + wave * 16;
    if (m0 >= M) return;
    const int q = lane >> 4;
    const int arow = m0 + (lane & 15);
    f32x4 acc[8] = {};
#pragma unroll
    for (int ks = 0; ks < 8; ++ks) {
        const float* ap = x + (size_t)arow * IN_DIM + ks * 32 + q * 8;
        f32x4 f0 = *(const f32x4*)(ap);
        f32x4 f1 = *(const f32x4*)(ap + 4);
        f16x8 a = { (_Float16)f0.x, (_Float16)f0.y, (_Float16)f0.z, (_Float16)f0.w,
                    (_Float16)f1.x, (_Float16)f1.y, (_Float16)f1.z, (_Float16)f1.w };
        const __half* bbase = W1frag + ((size_t)(ks * 8) * 64 + lane) * 8;
#pragma unroll
        for (int nt = 0; nt < 8; ++nt) {
            f16x8 bfrag = *(const f16x8*)(bbase + (size_t)nt * 64 * 8);
            acc[nt] = __builtin_amdgcn_mfma_f32_16x16x32_f16(a, bfrag, acc[nt], 0, 0, 0);
        }
    }
    float dv[4];
#pragma unroll
    for (int r = 0; r < 4; ++r) dv[r] = dinv[m0 + q * 4 + r];
#pragma unroll
    for (int nt = 0; nt < 8; ++nt) {
        int col = nt * 16 + (lane & 15);
        __half* cq = C + (size_t)(col >> 5) * M * QF + (col & 31);
#pragma unroll
        for (int r = 0; r < 4; ++r)
            cq[(size_t)(m0 + q * 4 + r) * QF] = __float2half(acc[nt][r] * dv[r]);
    }
}

// ---- GEMM2 MFMA: t2q[4][M][32] = fp16( dinv[m] * (h[M,128] @ Wcat)[m] );
//      A read from quarter-split h (ks*32 chunk == quarter ks) ----
__global__ __launch_bounds__(256) void k_gemm2_mfma(const __half* __restrict__ A,
                                                    const __half* __restrict__ Wcfrag,
                                                    const float* __restrict__ dinv,
                                                    __half* __restrict__ C, int M) {
    const int wave = threadIdx.x >> 6;
    const int lane = threadIdx.x & 63;
    const int m0 = blockIdx.x * 64 + wave * 16;
    if (m0 >= M) return;
    const int q = lane >> 4;
    const int arow = m0 + (lane & 15);
    f32x4 acc[8] = {};
#pragma unroll
    for (int ks = 0; ks < 4; ++ks) {
        f16x8 a = *(const f16x8*)(A + (size_t)ks * M * QF + (size_t)arow * QF + q * 8);
        const __half* bbase = Wcfrag + ((size_t)(ks * 8) * 64 + lane) * 8;
#pragma unroll
        for (int nt = 0; nt < 8; ++nt) {
            f16x8 bfrag = *(const f16x8*)(bbase + (size_t)nt * 64 * 8);
            acc[nt] = __builtin_amdgcn_mfma_f32_16x16x32_f16(a, bfrag, acc[nt], 0, 0, 0);
        }
    }
    float dv[4];
#pragma unroll
    for (int r = 0; r < 4; ++r) dv[r] = dinv[m0 + q * 4 + r];
#pragma unroll
    for (int nt = 0; nt < 8; ++nt) {
        int col = nt * 16 + (lane & 15);
        __half* cq = C + (size_t)(col >> 5) * M * QF + (col & 31);
#pragma unroll
        for (int r = 0; r < 4; ++r)
            cq[(size_t)(m0 + q * 4 + r) * QF] = __float2half(acc[nt][r] * dv[r]);
    }
}

// ---- conv1 gather, quarter-split: wave = one (node, quarter); 16 slots x 4
// lanes x 16B. Table rows pre-scaled by dinv[src] -> inner loop is pure add.
// Quarter = blockIdx.x / NBW (slow dim) keeps one 3.2MB quarter L2-resident. ----
__global__ __launch_bounds__(256) void k_gather1(const int* __restrict__ rs,
                                                 const int* __restrict__ re,
                                                 const int* __restrict__ ssrc,
                                                 const float* __restrict__ dinv,
                                                 const __half* __restrict__ t,
                                                 const float* __restrict__ b1,
                                                 __half* __restrict__ h,
                                                 int N, int NBW) {
    const int wave = threadIdx.x >> 6;
    const int lane = threadIdx.x & 63;
    const int q = blockIdx.x / NBW;
    const int node = (blockIdx.x - q * NBW) * 4 + wave;
    if (node >= N) return;
    const int slot = lane >> 2;     // 0..15: edge slot
    const int c4 = lane & 3;        // 16B chunk within 64B quarter row
    const __half* tq = t + (size_t)q * N * QF;
    float acc[8] = {};
    int e = rs[node] + slot, end = re[node];
    for (; e + 16 < end; e += 32) {
        int s0 = ssrc[e], s1 = ssrc[e + 16];
        f16x8 v0 = *(const f16x8*)(tq + (size_t)s0 * QF + c4 * 8);
        f16x8 v1 = *(const f16x8*)(tq + (size_t)s1 * QF + c4 * 8);
#pragma unroll
        for (int j = 0; j < 8; ++j)
            acc[j] += (float)v0[j] + (float)v1[j];
    }
    if (e < end) {
        int s = ssrc[e];
        f16x8 v = *(const f16x8*)(tq + (size_t)s * QF + c4 * 8);
#pragma unroll
        for (int j = 0; j < 8; ++j) acc[j] += (float)v[j];
    }
#pragma unroll
    for (int j = 0; j < 8; ++j) {
        acc[j] += __shfl_xor(acc[j], 4, 64);
        acc[j] += __shfl_xor(acc[j], 8, 64);
        acc[j] += __shfl_xor(acc[j], 16, 64);
        acc[j] += __shfl_xor(acc[j], 32, 64);
    }
    if (lane < 4) {
        float di = dinv[node];
        f16x8 sv = *(const f16x8*)(tq + (size_t)node * QF + lane * 8);
        const float* bp = b1 + q * QF + lane * 8;
        f32x4 bA = *(const f32x4*)(bp);
        f32x4 bB = *(const f32x4*)(bp + 4);
        float bb[8] = { bA.x, bA.y, bA.z, bA.w, bB.x, bB.y, bB.z, bB.w };
        f16x8 o;
#pragma unroll
        for (int j = 0; j < 8; ++j) {
            float val = (acc[j] + (float)sv[j]) * di + bb[j];
            o[j] = (_Float16)fmaxf(val, 0.f);
        }
        __builtin_nontemporal_store(
            o, (f16x8*)(h + (size_t)q * N * QF + (size_t)node * QF + lane * 8));
    }
}

// ---- conv2 gather, quarter-split; fp32 out: q0,1 -> mu cols 0-63, q2,3 -> ls ----
__global__ __launch_bounds__(256) void k_gather2(const int* __restrict__ rs,
                                                 const int* __restrict__ re,
                                                 const int* __restrict__ ssrc,
                                                 const float* __restrict__ dinv,
                                                 const __half* __restrict__ t,
                                                 const float* __restrict__ bmu,
                                                 const float* __restrict__ bls,
                                                 float* __restrict__ out,
                                                 int N, int NBW) {
    const int wave = threadIdx.x >> 6;
    const int lane = threadIdx.x & 63;
    const int q = blockIdx.x / NBW;
    const int node = (blockIdx.x - q * NBW) * 4 + wave;
    if (node >= N) return;
    const int slot = lane >> 2;
    const int c4 = lane & 3;
    const __half* tq = t + (size_t)q * N * QF;
    float acc[8] = {};
    int e = rs[node] + slot, end = re[node];
    for (; e + 16 < end; e += 32) {
        int s0 = ssrc[e], s1 = ssrc[e + 16];
        f16x8 v0 = *(const f16x8*)(tq + (size_t)s0 * QF + c4 * 8);
        f16x8 v1 = *(const f16x8*)(tq + (size_t)s1 * QF + c4 * 8);
#pragma unroll
        for (int j = 0; j < 8; ++j)
            acc[j] += (float)v0[j] + (float)v1[j];
    }
    if (e < end) {
        int s = ssrc[e];
        f16x8 v = *(const f16x8*)(tq + (size_t)s * QF + c4 * 8);
#pragma unroll
        for (int j = 0; j < 8; ++j) acc[j] += (float)v[j];
    }
#pragma unroll
    for (int j = 0; j < 8; ++j) {
        acc[j] += __shfl_xor(acc[j], 4, 64);
        acc[j] += __shfl_xor(acc[j], 8, 64);
        acc[j] += __shfl_xor(acc[j], 16, 64);
        acc[j] += __shfl_xor(acc[j], 32, 64);
    }
    if (lane < 4) {
        float di = dinv[node];
        f16x8 sv = *(const f16x8*)(tq + (size_t)node * QF + lane * 8);
        const float* bp = (q < 2) ? (bmu + q * QF + lane * 8)
                                  : (bls + (q - 2) * QF + lane * 8);
        float* op = (q < 2)
            ? (out + (size_t)node * F2 + q * QF + lane * 8)
            : (out + (size_t)N * F2 + (size_t)node * F2 + (q - 2) * QF + lane * 8);
        f32x4 bA = *(const f32x4*)(bp);
        f32x4 bB = *(const f32x4*)(bp + 4);
        float bb[8] = { bA.x, bA.y, bA.z, bA.w, bB.x, bB.y, bB.z, bB.w };
        float r[8];
#pragma unroll
        for (int j = 0; j < 8; ++j)
            r[j] = (acc[j] + (float)sv[j]) * di + bb[j];
        f32x4 oA = { r[0], r[1], r[2], r[3] };
        f32x4 oB = { r[4], r[5], r[6], r[7] };
        __builtin_nontemporal_store(oA, (f32x4*)(op));
        __builtin_nontemporal_store(oB, (f32x4*)(op + 4));
    }
}

extern "C" void kernel_launch(void* const* d_in, const int* in_sizes, int n_in,
                              void* d_out, int out_size, void* d_ws, size_t ws_size,
                              hipStream_t stream) {
    const float* x   = (const float*)d_in[0];
    const int*   ei  = (const int*)d_in[1];
    const float* W1  = (const float*)d_in[3];
    const float* b1  = (const float*)d_in[4];
    const float* Wmu = (const float*)d_in[5];
    const float* bmu = (const float*)d_in[6];
    const float* Wls = (const float*)d_in[7];
    const float* bls = (const float*)d_in[8];

    const int N = in_sizes[0] / IN_DIM;
    const int E = in_sizes[1] / 2;
    const int* src = ei;
    const int* dst = ei + E;
    float* out = (float*)d_out;
    const int nbuck = cdiv_i(N, BN);   // 391

    // ---- workspace carve (units: 4B slots) ----
    size_t off = 0;
    auto carve = [&](size_t n) { size_t o = off; off += (n + 3) & ~(size_t)3; return o; };
    float* ws = (float*)d_ws;
    float*  dinv   =        ws + carve(N);
    int*    rs     = (int*)(ws + carve(N));
    int*    re     = (int*)(ws + carve(N));
    int*    bcur   = (int*)(ws + carve(512));
    int*    ssrc   = (int*)(ws + carve((size_t)nbuck * CAP));
    __half* t16    = (__half*)(ws + carve((size_t)N * F1 / 2));  // [4][N][32]
    __half* h16    = (__half*)(ws + carve((size_t)N * F1 / 2));  // [4][N][32]
    __half* W1frag = (__half*)(ws + carve(8 * 8 * 64 * 8 / 2));
    __half* Wcfrag = (__half*)(ws + carve(4 * 8 * 64 * 8 / 2));
    (void)ws_size;
    // pairs (nbuck*CAP ints = 7.4MB) alias t16 (12.8MB): consumed by
    // k_bucket_build before GEMM1 writes t16.
    int* pairs = (int*)t16;
    __half* t2_16 = t16;   // GEMM2 output reuses t16 (dead after gather1)

    k_prep_frags<<<cdiv_i(8 * 8 * 64 + 4 * 8 * 64, 256), 256, 0, stream>>>(
        W1, Wmu, Wls, W1frag, Wcfrag);

    // CSR build: memset + LDS-staged binning (packed pairs) + bucket_build
    hipMemsetAsync(bcur, 0, sizeof(int) * 512, stream);
    k_binning<<<cdiv_i(E, BIN_EDGES), 512, 0, stream>>>(src, dst, bcur, pairs, E);
    k_bucket_build<<<nbuck, 512, 0, stream>>>(pairs, bcur, dinv, rs, re, ssrc, N);

    const int NBW = cdiv_i(N, 4);   // node-blocks per quarter pass

    // GEMM1 (MFMA): t16 = fp16(dinv * (x @ W1)), quarter-split layout
    k_gemm1_mfma<<<cdiv_i(N, 64), 256, 0, stream>>>(x, W1frag, dinv, t16, N);
    // conv1 aggregate + bias + relu -> h16 (quarter-split)
    k_gather1<<<4 * NBW, 256, 0, stream>>>(rs, re, ssrc, dinv, t16, b1, h16, N, NBW);
    // GEMM2 (MFMA): t2 = fp16(dinv * (h @ Wcat)), quarter-split
    k_gemm2_mfma<<<cdiv_i(N, 64), 256, 0, stream>>>(h16, Wcfrag, dinv, t2_16, N);
    // conv2 aggregate -> out (mu || logstd), fp32
    k_gather2<<<4 * NBW, 256, 0, stream>>>(rs, re, ssrc, dinv, t2_16, bmu, bls,
                                           out, N, NBW);
}

// Round 5
// 302.656 us; speedup vs baseline: 1.0752x; 1.0752x over previous
//
#include <hip/hip_runtime.h>
#include <hip/hip_fp16.h>

// VGAE on GCN: N=50000, E=1.6M, IN=256, HIDDEN=128, OUT=64.
// Round 15: MFMA-gather, tr-read LINEAR addressing. Quarter-split tables
// ([4][N][32] f16, 3.2MB/quarter, L2-resident per pass). Per 32-edge chunk:
// stage rows into wave-private LDS (edge-major, [4edge][16feat] subtiled) via
// global_load_lds (2x 16B/lane), then ds_read_b64_tr_b16 with va = base+8*lane
// (each lane = one 8B row ptr; HW does the 16x4->4x16 group transpose:
// lane l elem j = elem (l&15)+16j+64*(l>>4) of the 512-elem block).
// mfma(ones, B, acc) x2 sums 32 edges x 32 feats, f32 accumulate. A=ones makes
// the edge->k permutation irrelevant; no shuffle epilogue. OOB tail -> zrow.

#define IN_DIM 256
#define F1 128   // HIDDEN
#define F2 64    // OUT
#define QF 32    // features per quarter (F1/4)
#define BN 128        // nodes per bucket
#define CAP 4736      // bucket capacity: mean 4096, +10 sigma
#define BIN_EDGES 4096  // edges per binning block (512 thr x 8)

typedef _Float16 f16x8 __attribute__((ext_vector_type(8)));
typedef _Float16 f16x4 __attribute__((ext_vector_type(4)));
typedef float f32x4 __attribute__((ext_vector_type(4)));

static inline int cdiv_i(int a, int b) { return (a + b - 1) / b; }

__device__ static inline uint32_t lds_addr(const void* p) {
    return (uint32_t)(size_t)(const __attribute__((address_space(3))) void*)p;
}

// ---- weight prep: fragment-ordered fp16 buffers ----
__global__ void k_prep_frags(const float* __restrict__ W1,
                             const float* __restrict__ Wmu,
                             const float* __restrict__ Wls,
                             __half* __restrict__ W1frag,
                             __half* __restrict__ Wcfrag) {
    int t = blockIdx.x * blockDim.x + threadIdx.x;
    if (t < 8 * 8 * 64) {
        int lane = t & 63, nt = (t >> 6) & 7, ks = t >> 9;
        int k0 = ks * 32 + ((lane >> 4) << 3);
        int n = nt * 16 + (lane & 15);
#pragma unroll
        for (int j = 0; j < 8; ++j)
            W1frag[(size_t)t * 8 + j] = __float2half(W1[(k0 + j) * F1 + n]);
    } else if (t < 8 * 8 * 64 + 4 * 8 * 64) {
        int u = t - 8 * 8 * 64;
        int lane = u & 63, nt = (u >> 6) & 7, ks = u >> 9;
        int k0 = ks * 32 + ((lane >> 4) << 3);
        int c = nt * 16 + (lane & 15);
        const float* W = (c < F2) ? (Wmu + c) : (Wls + (c - F2));
#pragma unroll
        for (int j = 0; j < 8; ++j)
            Wcfrag[(size_t)u * 8 + j] = __float2half(W[(k0 + j) * F2]);
    }
}

// ---- pass 1: bin edges by dst>>7; packed pair = (dst&127)<<16 | src ----
__global__ __launch_bounds__(512) void k_binning(const int* __restrict__ src,
                                                 const int* __restrict__ dst,
                                                 int* __restrict__ bcur,
                                                 int* __restrict__ pairs, int E) {
    __shared__ int hcnt[512];
    __shared__ int hrank[512];
    __shared__ int hbase[512];
    __shared__ int lbase[512];
    __shared__ int stage[BIN_EDGES];
    __shared__ int gaddr[BIN_EDGES];
    const int tid = threadIdx.x;
    hcnt[tid] = 0; hrank[tid] = 0;
    __syncthreads();
    const int e0 = blockIdx.x * BIN_EDGES;
    int s_[8], d_[8];
#pragma unroll
    for (int it = 0; it < 8; ++it) {
        int e = e0 + it * 512 + tid;
        if (e < E) {
            s_[it] = src[e];
            d_[it] = dst[e];
            atomicAdd(&hcnt[d_[it] >> 7], 1);
        } else {
            d_[it] = -1;
        }
    }
    __syncthreads();
    int v = hcnt[tid];
    lbase[tid] = v;
    __syncthreads();
    for (int ofs = 1; ofs < 512; ofs <<= 1) {
        int add = (tid >= ofs) ? lbase[tid - ofs] : 0;
        __syncthreads();
        lbase[tid] += add;
        __syncthreads();
    }
    int total = lbase[511];
    int excl = lbase[tid] - v;
    __syncthreads();
    lbase[tid] = excl;
    hbase[tid] = v ? atomicAdd(&bcur[tid], v) : 0;
    __syncthreads();
#pragma unroll
    for (int it = 0; it < 8; ++it) {
        if (d_[it] >= 0) {
            int b = d_[it] >> 7;
            int r = atomicAdd(&hrank[b], 1);
            int li = lbase[b] + r;
            stage[li] = ((d_[it] & (BN - 1)) << 16) | s_[it];
            gaddr[li] = b * CAP + hbase[b] + r;
        }
    }
    __syncthreads();
    for (int i = tid; i < total; i += 512)
        pairs[gaddr[i]] = stage[i];
}

// ---- pass 2: per-bucket histogram -> scan -> dinv + [rs,re) + staged ssrc ----
__global__ __launch_bounds__(512) void k_bucket_build(const int* __restrict__ pairs,
                                                      const int* __restrict__ bcur,
                                                      float* __restrict__ dinv,
                                                      int* __restrict__ rs,
                                                      int* __restrict__ re,
                                                      int* __restrict__ ssrc, int N) {
    __shared__ int hist[BN];
    __shared__ int offs[BN];
    __shared__ int stage[CAP];
    const int b = blockIdx.x;
    const int n0 = b * BN;
    const int tid = threadIdx.x;
    const int pbase = b * CAP;
    const int cnt = min(bcur[b], CAP);
    if (tid < BN) hist[tid] = 0;
    __syncthreads();
    for (int e = tid; e < cnt; e += 512)
        atomicAdd(&hist[pairs[pbase + e] >> 16], 1);
    __syncthreads();
    if (tid < BN) offs[tid] = hist[tid];
    __syncthreads();
    for (int ofs = 1; ofs < BN; ofs <<= 1) {
        int add = 0;
        if (tid < BN && tid >= ofs) add = offs[tid - ofs];
        __syncthreads();
        if (tid < BN) offs[tid] += add;
        __syncthreads();
    }
    if (tid < BN) {
        int incl = offs[tid];
        int excl = incl - hist[tid];
        int n = n0 + tid;
        if (n < N) {
            dinv[n] = rsqrtf((float)hist[tid] + 1.0f);   // +1 self-loop
            rs[n] = pbase + excl;
            re[n] = pbase + incl;
        }
        offs[tid] = excl;
    }
    __syncthreads();
    for (int e = tid; e < cnt; e += 512) {
        int p = pairs[pbase + e];
        int idx = atomicAdd(&offs[p >> 16], 1);
        stage[idx] = p & 0xFFFF;
    }
    __syncthreads();
    for (int i = tid; i < cnt; i += 512) ssrc[pbase + i] = stage[i];
}

// ---- GEMM1 MFMA: tq[4][M][32] = fp16( dinv[m] * (x[M,256] @ W1)[m] ) ----
__global__ __launch_bounds__(256) void k_gemm1_mfma(const float* __restrict__ x,
                                                    const __half* __restrict__ W1frag,
                                                    const float* __restrict__ dinv,
                                                    __half* __restrict__ C, int M) {
    const int wave = threadIdx.x >> 6;
    const int lane = threadIdx.x & 63;
    const int m0 = blockIdx.x * 64 + wave * 16;
    if (m0 >= M) return;
    const int q = lane >> 4;
    const int arow = m0 + (lane & 15);
    f32x4 acc[8] = {};
#pragma unroll
    for (int ks = 0; ks < 8; ++ks) {
        const float* ap = x + (size_t)arow * IN_DIM + ks * 32 + q * 8;
        f32x4 f0 = *(const f32x4*)(ap);
        f32x4 f1 = *(const f32x4*)(ap + 4);
        f16x8 a = { (_Float16)f0.x, (_Float16)f0.y, (_Float16)f0.z, (_Float16)f0.w,
                    (_Float16)f1.x, (_Float16)f1.y, (_Float16)f1.z, (_Float16)f1.w };
        const __half* bbase = W1frag + ((size_t)(ks * 8) * 64 + lane) * 8;
#pragma unroll
        for (int nt = 0; nt < 8; ++nt) {
            f16x8 bfrag = *(const f16x8*)(bbase + (size_t)nt * 64 * 8);
            acc[nt] = __builtin_amdgcn_mfma_f32_16x16x32_f16(a, bfrag, acc[nt], 0, 0, 0);
        }
    }
    float dv[4];
#pragma unroll
    for (int r = 0; r < 4; ++r) dv[r] = dinv[m0 + q * 4 + r];
#pragma unroll
    for (int nt = 0; nt < 8; ++nt) {
        int col = nt * 16 + (lane & 15);
        __half* cq = C + (size_t)(col >> 5) * M * QF + (col & 31);
#pragma unroll
        for (int r = 0; r < 4; ++r)
            cq[(size_t)(m0 + q * 4 + r) * QF] = __float2half(acc[nt][r] * dv[r]);
    }
}

// ---- GEMM2 MFMA: t2q[4][M][32] = fp16( dinv[m] * (h[M,128] @ Wcat)[m] );
//      A read from quarter-split h (ks*32 chunk == quarter ks) ----
__global__ __launch_bounds__(256) void k_gemm2_mfma(const __half* __restrict__ A,
                                                    const __half* __restrict__ Wcfrag,
                                                    const float* __restrict__ dinv,
                                                    __half* __restrict__ C, int M) {
    const int wave = threadIdx.x >> 6;
    const int lane = threadIdx.x & 63;
    const int m0 = blockIdx.x * 64 + wave * 16;
    if (m0 >= M) return;
    const int q = lane >> 4;
    const int arow = m0 + (lane & 15);
    f32x4 acc[8] = {};
#pragma unroll
    for (int ks = 0; ks < 4; ++ks) {
        f16x8 a = *(const f16x8*)(A + (size_t)ks * M * QF + (size_t)arow * QF + q * 8);
        const __half* bbase = Wcfrag + ((size_t)(ks * 8) * 64 + lane) * 8;
#pragma unroll
        for (int nt = 0; nt < 8; ++nt) {
            f16x8 bfrag = *(const f16x8*)(bbase + (size_t)nt * 64 * 8);
            acc[nt] = __builtin_amdgcn_mfma_f32_16x16x32_f16(a, bfrag, acc[nt], 0, 0, 0);
        }
    }
    float dv[4];
#pragma unroll
    for (int r = 0; r < 4; ++r) dv[r] = dinv[m0 + q * 4 + r];
#pragma unroll
    for (int nt = 0; nt < 8; ++nt) {
        int col = nt * 16 + (lane & 15);
        __half* cq = C + (size_t)(col >> 5) * M * QF + (col & 31);
#pragma unroll
        for (int r = 0; r < 4; ++r)
            cq[(size_t)(m0 + q * 4 + r) * QF] = __float2half(acc[nt][r] * dv[r]);
    }
}

// ---- MFMA-gather chunk body (shared by both gathers) ----
// Stage 32 quarter-rows (64B) edge-major: block0 = feats 0-15 (bytes [0,1024)),
// block1 = feats 16-31 ([1024,2048)); each block = 8 subtiles of [4e][16f].
// tr-read with va = base + 8*lane: 16-lane group g reads subtile g (128B),
// delivering lane l elem j = edge 4g+j, feat l&15 (+offset walks subtiles).
// bf0/bf1 cover edges 0-31 exactly once per column -> mfma(ones, bf, acc).
#define GATHER_CHUNK(ACC0, ACC1)                                               \
    {                                                                          \
        const int eidx = e0 + row2;                                            \
        const __half* gp = (eidx < eend)                                       \
            ? (tq + (size_t)ssrc[eidx] * QF + halfo) : (zrow + halfo);         \
        __builtin_amdgcn_global_load_lds(                                      \
            (const __attribute__((address_space(1))) void*)gp,                 \
            (__attribute__((address_space(3))) void*)lbase, 16, 0, 0);         \
        __builtin_amdgcn_global_load_lds(                                      \
            (const __attribute__((address_space(1))) void*)(gp + 16),          \
            (__attribute__((address_space(3))) void*)(lbase + 512), 16, 0, 0); \
        asm volatile("s_waitcnt vmcnt(0)" ::: "memory");                       \
        f16x4 r0, r1, r2, r3;                                                  \
        asm volatile(                                                          \
            "ds_read_b64_tr_b16 %0, %4 offset:0\n\t"                           \
            "ds_read_b64_tr_b16 %1, %4 offset:512\n\t"                         \
            "ds_read_b64_tr_b16 %2, %4 offset:1024\n\t"                        \
            "ds_read_b64_tr_b16 %3, %4 offset:1536\n\t"                        \
            "s_waitcnt lgkmcnt(0)"                                             \
            : "=&v"(r0), "=&v"(r1), "=&v"(r2), "=&v"(r3)                       \
            : "v"(va) : "memory");                                             \
        __builtin_amdgcn_sched_barrier(0);                                     \
        f16x8 bf0, bf1;                                                        \
        _Pragma("unroll")                                                      \
        for (int j = 0; j < 4; ++j) {                                          \
            bf0[j] = r0[j]; bf0[j + 4] = r1[j];                                \
            bf1[j] = r2[j]; bf1[j + 4] = r3[j];                                \
        }                                                                      \
        ACC0 = __builtin_amdgcn_mfma_f32_16x16x32_f16(ones, bf0, ACC0, 0, 0, 0);\
        ACC1 = __builtin_amdgcn_mfma_f32_16x16x32_f16(ones, bf1, ACC1, 0, 0, 0);\
    }

// ---- conv1 gather (MFMA): h[q][node][f] = relu((sum + self)*di + b1) ----
__global__ __launch_bounds__(256) void k_gather1(const int* __restrict__ rs,
                                                 const int* __restrict__ re,
                                                 const int* __restrict__ ssrc,
                                                 const float* __restrict__ dinv,
                                                 const __half* __restrict__ t,
                                                 const __half* __restrict__ zrow,
                                                 const float* __restrict__ b1,
                                                 __half* __restrict__ h,
                                                 int N, int NBW) {
    __shared__ __half smem[4][1024];   // 2KB per wave
    const int wave = threadIdx.x >> 6;
    const int lane = threadIdx.x & 63;
    const int q = blockIdx.x / NBW;
    const int node = (blockIdx.x - q * NBW) * 4 + wave;
    if (node >= N) return;
    const int row2 = lane >> 1;            // edge slot 0..31
    const int halfo = (lane & 1) * 8;      // f16 offset of 16B half-row
    const __half* tq = t + (size_t)q * N * QF;
    __half* lbase = &smem[wave][0];
    const uint32_t va = lds_addr(lbase) + 8u * lane;   // linear 8B row per lane
    const f16x8 ones = { (_Float16)1.f, (_Float16)1.f, (_Float16)1.f, (_Float16)1.f,
                         (_Float16)1.f, (_Float16)1.f, (_Float16)1.f, (_Float16)1.f };
    f32x4 acc0 = {}, acc1 = {};
    const int eend = re[node];
    for (int e0 = rs[node]; e0 < eend; e0 += 32)
        GATHER_CHUNK(acc0, acc1)
    if (lane < 32) {
        const int feat = lane;             // blk = lane>>4, col = lane&15
        float aval = (lane < 16) ? acc0[0] : acc1[0];
        float di = dinv[node];
        float self = __half2float(tq[(size_t)node * QF + feat]);
        float val = (aval + self) * di + b1[q * QF + feat];
        h[(size_t)q * N * QF + (size_t)node * QF + feat] =
            __float2half(fmaxf(val, 0.f));
    }
}

// ---- conv2 gather (MFMA): fp32 out; q0,1 -> mu, q2,3 -> logstd ----
__global__ __launch_bounds__(256) void k_gather2(const int* __restrict__ rs,
                                                 const int* __restrict__ re,
                                                 const int* __restrict__ ssrc,
                                                 const float* __restrict__ dinv,
                                                 const __half* __restrict__ t,
                                                 const __half* __restrict__ zrow,
                                                 const float* __restrict__ bmu,
                                                 const float* __restrict__ bls,
                                                 float* __restrict__ out,
                                                 int N, int NBW) {
    __shared__ __half smem[4][1024];
    const int wave = threadIdx.x >> 6;
    const int lane = threadIdx.x & 63;
    const int q = blockIdx.x / NBW;
    const int node = (blockIdx.x - q * NBW) * 4 + wave;
    if (node >= N) return;
    const int row2 = lane >> 1;
    const int halfo = (lane & 1) * 8;
    const __half* tq = t + (size_t)q * N * QF;
    __half* lbase = &smem[wave][0];
    const uint32_t va = lds_addr(lbase) + 8u * lane;   // linear 8B row per lane
    const f16x8 ones = { (_Float16)1.f, (_Float16)1.f, (_Float16)1.f, (_Float16)1.f,
                         (_Float16)1.f, (_Float16)1.f, (_Float16)1.f, (_Float16)1.f };
    f32x4 acc0 = {}, acc1 = {};
    const int eend = re[node];
    for (int e0 = rs[node]; e0 < eend; e0 += 32)
        GATHER_CHUNK(acc0, acc1)
    if (lane < 32) {
        const int feat = lane;
        float aval = (lane < 16) ? acc0[0] : acc1[0];
        float di = dinv[node];
        float self = __half2float(tq[(size_t)node * QF + feat]);
        float bias = (q < 2) ? bmu[q * QF + feat] : bls[(q - 2) * QF + feat];
        float val = (aval + self) * di + bias;
        float* op = (q < 2)
            ? (out + (size_t)node * F2 + q * QF + feat)
            : (out + (size_t)N * F2 + (size_t)node * F2 + (q - 2) * QF + feat);
        *op = val;
    }
}

extern "C" void kernel_launch(void* const* d_in, const int* in_sizes, int n_in,
                              void* d_out, int out_size, void* d_ws, size_t ws_size,
                              hipStream_t stream) {
    const float* x   = (const float*)d_in[0];
    const int*   ei  = (const int*)d_in[1];
    const float* W1  = (const float*)d_in[3];
    const float* b1  = (const float*)d_in[4];
    const float* Wmu = (const float*)d_in[5];
    const float* bmu = (const float*)d_in[6];
    const float* Wls = (const float*)d_in[7];
    const float* bls = (const float*)d_in[8];

    const int N = in_sizes[0] / IN_DIM;
    const int E = in_sizes[1] / 2;
    const int* src = ei;
    const int* dst = ei + E;
    float* out = (float*)d_out;
    const int nbuck = cdiv_i(N, BN);   // 391

    // ---- workspace carve (units: 4B slots) ----
    size_t off = 0;
    auto carve = [&](size_t n) { size_t o = off; off += (n + 3) & ~(size_t)3; return o; };
    float* ws = (float*)d_ws;
    float*  dinv   =        ws + carve(N);
    int*    rs     = (int*)(ws + carve(N));
    int*    re     = (int*)(ws + carve(N));
    int*    bcur   = (int*)(ws + carve(512));
    __half* zrow   = (__half*)(ws + carve(16));   // 64B zero row (contiguous after bcur)
    int*    ssrc   = (int*)(ws + carve((size_t)nbuck * CAP));
    __half* t16    = (__half*)(ws + carve((size_t)N * F1 / 2));  // [4][N][32]
    __half* h16    = (__half*)(ws + carve((size_t)N * F1 / 2));  // [4][N][32]
    __half* W1frag = (__half*)(ws + carve(8 * 8 * 64 * 8 / 2));
    __half* Wcfrag = (__half*)(ws + carve(4 * 8 * 64 * 8 / 2));
    (void)ws_size;
    // pairs (nbuck*CAP ints = 7.4MB) alias t16 (12.8MB): consumed by
    // k_bucket_build before GEMM1 writes t16.
    int* pairs = (int*)t16;
    __half* t2_16 = t16;   // GEMM2 output reuses t16 (dead after gather1)

    k_prep_frags<<<cdiv_i(8 * 8 * 64 + 4 * 8 * 64, 256), 256, 0, stream>>>(
        W1, Wmu, Wls, W1frag, Wcfrag);

    // CSR build: memset (bcur + zrow, contiguous) + binning + bucket_build
    hipMemsetAsync(bcur, 0, sizeof(int) * 512 + 64, stream);
    k_binning<<<cdiv_i(E, BIN_EDGES), 512, 0, stream>>>(src, dst, bcur, pairs, E);
    k_bucket_build<<<nbuck, 512, 0, stream>>>(pairs, bcur, dinv, rs, re, ssrc, N);

    const int NBW = cdiv_i(N, 4);   // node-blocks per quarter pass

    // GEMM1 (MFMA): t16 = fp16(dinv * (x @ W1)), quarter-split layout
    k_gemm1_mfma<<<cdiv_i(N, 64), 256, 0, stream>>>(x, W1frag, dinv, t16, N);
    // conv1 aggregate (MFMA-gather) + bias + relu -> h16
    k_gather1<<<4 * NBW, 256, 0, stream>>>(rs, re, ssrc, dinv, t16, zrow,
                                           b1, h16, N, NBW);
    // GEMM2 (MFMA): t2 = fp16(dinv * (h @ Wcat)), quarter-split
    k_gemm2_mfma<<<cdiv_i(N, 64), 256, 0, stream>>>(h16, Wcfrag, dinv, t2_16, N);
    // conv2 aggregate (MFMA-gather) -> out (mu || logstd), fp32
    k_gather2<<<4 * NBW, 256, 0, stream>>>(rs, re, ssrc, dinv, t2_16, zrow,
                                           bmu, bls, out, N, NBW);
}

// Round 6
// 293.925 us; speedup vs baseline: 1.1071x; 1.0297x over previous
//
#include <hip/hip_runtime.h>
#include <hip/hip_fp16.h>

// VGAE on GCN: N=50000, E=1.6M, IN=256, HIDDEN=128, OUT=64.
// Round 16: grouped MFMA-gather. Wave = (16-node group, quarter). CSR edges of
// the group are contiguous [rs[nb], re[nb+15]). Per 32-edge chunk: stage rows
// to LDS (2x global_load_lds 16B/lane, double-buffered), ds_read_b64_tr_b16
// (linear base+8*lane, verified R15) -> B[32x16] x2; A = 0/1 membership matrix
// (A[r][k] = edge in node r's range, built in regs via compare vs per-lane
// rs/re, mapped through tr-read edge permutation pi(8g+j)=4g+(j&3)+16*(j>>2)).
// D[r][col] accumulates per-node sums for 16 nodes at once. Pipelined with
// counted vmcnt(3) (never 0 mid-loop) + ssrc prefetch 3 chunks ahead.

#define IN_DIM 256
#define F1 128   // HIDDEN
#define F2 64    // OUT
#define QF 32    // features per quarter (F1/4)
#define BN 128        // nodes per bucket
#define CAP 4736      // bucket capacity: mean 4096, +10 sigma
#define BIN_EDGES 4096  // edges per binning block (512 thr x 8)

typedef _Float16 f16x8 __attribute__((ext_vector_type(8)));
typedef _Float16 f16x4 __attribute__((ext_vector_type(4)));
typedef float f32x4 __attribute__((ext_vector_type(4)));

static inline int cdiv_i(int a, int b) { return (a + b - 1) / b; }

__device__ static inline uint32_t lds_addr(const void* p) {
    return (uint32_t)(size_t)(const __attribute__((address_space(3))) void*)p;
}

// ---- weight prep: fragment-ordered fp16 buffers ----
__global__ void k_prep_frags(const float* __restrict__ W1,
                             const float* __restrict__ Wmu,
                             const float* __restrict__ Wls,
                             __half* __restrict__ W1frag,
                             __half* __restrict__ Wcfrag) {
    int t = blockIdx.x * blockDim.x + threadIdx.x;
    if (t < 8 * 8 * 64) {
        int lane = t & 63, nt = (t >> 6) & 7, ks = t >> 9;
        int k0 = ks * 32 + ((lane >> 4) << 3);
        int n = nt * 16 + (lane & 15);
#pragma unroll
        for (int j = 0; j < 8; ++j)
            W1frag[(size_t)t * 8 + j] = __float2half(W1[(k0 + j) * F1 + n]);
    } else if (t < 8 * 8 * 64 + 4 * 8 * 64) {
        int u = t - 8 * 8 * 64;
        int lane = u & 63, nt = (u >> 6) & 7, ks = u >> 9;
        int k0 = ks * 32 + ((lane >> 4) << 3);
        int c = nt * 16 + (lane & 15);
        const float* W = (c < F2) ? (Wmu + c) : (Wls + (c - F2));
#pragma unroll
        for (int j = 0; j < 8; ++j)
            Wcfrag[(size_t)u * 8 + j] = __float2half(W[(k0 + j) * F2]);
    }
}

// ---- pass 1: bin edges by dst>>7; packed pair = (dst&127)<<16 | src ----
__global__ __launch_bounds__(512) void k_binning(const int* __restrict__ src,
                                                 const int* __restrict__ dst,
                                                 int* __restrict__ bcur,
                                                 int* __restrict__ pairs, int E) {
    __shared__ int hcnt[512];
    __shared__ int hrank[512];
    __shared__ int hbase[512];
    __shared__ int lbase[512];
    __shared__ int stage[BIN_EDGES];
    __shared__ int gaddr[BIN_EDGES];
    const int tid = threadIdx.x;
    hcnt[tid] = 0; hrank[tid] = 0;
    __syncthreads();
    const int e0 = blockIdx.x * BIN_EDGES;
    int s_[8], d_[8];
#pragma unroll
    for (int it = 0; it < 8; ++it) {
        int e = e0 + it * 512 + tid;
        if (e < E) {
            s_[it] = src[e];
            d_[it] = dst[e];
            atomicAdd(&hcnt[d_[it] >> 7], 1);
        } else {
            d_[it] = -1;
        }
    }
    __syncthreads();
    int v = hcnt[tid];
    lbase[tid] = v;
    __syncthreads();
    for (int ofs = 1; ofs < 512; ofs <<= 1) {
        int add = (tid >= ofs) ? lbase[tid - ofs] : 0;
        __syncthreads();
        lbase[tid] += add;
        __syncthreads();
    }
    int total = lbase[511];
    int excl = lbase[tid] - v;
    __syncthreads();
    lbase[tid] = excl;
    hbase[tid] = v ? atomicAdd(&bcur[tid], v) : 0;
    __syncthreads();
#pragma unroll
    for (int it = 0; it < 8; ++it) {
        if (d_[it] >= 0) {
            int b = d_[it] >> 7;
            int r = atomicAdd(&hrank[b], 1);
            int li = lbase[b] + r;
            stage[li] = ((d_[it] & (BN - 1)) << 16) | s_[it];
            gaddr[li] = b * CAP + hbase[b] + r;
        }
    }
    __syncthreads();
    for (int i = tid; i < total; i += 512)
        pairs[gaddr[i]] = stage[i];
}

// ---- pass 2: per-bucket histogram -> scan -> dinv + [rs,re) + staged ssrc ----
__global__ __launch_bounds__(512) void k_bucket_build(const int* __restrict__ pairs,
                                                      const int* __restrict__ bcur,
                                                      float* __restrict__ dinv,
                                                      int* __restrict__ rs,
                                                      int* __restrict__ re,
                                                      int* __restrict__ ssrc, int N) {
    __shared__ int hist[BN];
    __shared__ int offs[BN];
    __shared__ int stage[CAP];
    const int b = blockIdx.x;
    const int n0 = b * BN;
    const int tid = threadIdx.x;
    const int pbase = b * CAP;
    const int cnt = min(bcur[b], CAP);
    if (tid < BN) hist[tid] = 0;
    __syncthreads();
    for (int e = tid; e < cnt; e += 512)
        atomicAdd(&hist[pairs[pbase + e] >> 16], 1);
    __syncthreads();
    if (tid < BN) offs[tid] = hist[tid];
    __syncthreads();
    for (int ofs = 1; ofs < BN; ofs <<= 1) {
        int add = 0;
        if (tid < BN && tid >= ofs) add = offs[tid - ofs];
        __syncthreads();
        if (tid < BN) offs[tid] += add;
        __syncthreads();
    }
    if (tid < BN) {
        int incl = offs[tid];
        int excl = incl - hist[tid];
        int n = n0 + tid;
        if (n < N) {
            dinv[n] = rsqrtf((float)hist[tid] + 1.0f);   // +1 self-loop
            rs[n] = pbase + excl;
            re[n] = pbase + incl;
        }
        offs[tid] = excl;
    }
    __syncthreads();
    for (int e = tid; e < cnt; e += 512) {
        int p = pairs[pbase + e];
        int idx = atomicAdd(&offs[p >> 16], 1);
        stage[idx] = p & 0xFFFF;
    }
    __syncthreads();
    for (int i = tid; i < cnt; i += 512) ssrc[pbase + i] = stage[i];
}

// ---- GEMM1 MFMA: tq[4][M][32] = fp16( dinv[m] * (x[M,256] @ W1)[m] ) ----
__global__ __launch_bounds__(256) void k_gemm1_mfma(const float* __restrict__ x,
                                                    const __half* __restrict__ W1frag,
                                                    const float* __restrict__ dinv,
                                                    __half* __restrict__ C, int M) {
    const int wave = threadIdx.x >> 6;
    const int lane = threadIdx.x & 63;
    const int m0 = blockIdx.x * 64 + wave * 16;
    if (m0 >= M) return;
    const int q = lane >> 4;
    const int arow = m0 + (lane & 15);
    f32x4 acc[8] = {};
#pragma unroll
    for (int ks = 0; ks < 8; ++ks) {
        const float* ap = x + (size_t)arow * IN_DIM + ks * 32 + q * 8;
        f32x4 f0 = *(const f32x4*)(ap);
        f32x4 f1 = *(const f32x4*)(ap + 4);
        f16x8 a = { (_Float16)f0.x, (_Float16)f0.y, (_Float16)f0.z, (_Float16)f0.w,
                    (_Float16)f1.x, (_Float16)f1.y, (_Float16)f1.z, (_Float16)f1.w };
        const __half* bbase = W1frag + ((size_t)(ks * 8) * 64 + lane) * 8;
#pragma unroll
        for (int nt = 0; nt < 8; ++nt) {
            f16x8 bfrag = *(const f16x8*)(bbase + (size_t)nt * 64 * 8);
            acc[nt] = __builtin_amdgcn_mfma_f32_16x16x32_f16(a, bfrag, acc[nt], 0, 0, 0);
        }
    }
    float dv[4];
#pragma unroll
    for (int r = 0; r < 4; ++r) dv[r] = dinv[m0 + q * 4 + r];
#pragma unroll
    for (int nt = 0; nt < 8; ++nt) {
        int col = nt * 16 + (lane & 15);
        __half* cq = C + (size_t)(col >> 5) * M * QF + (col & 31);
#pragma unroll
        for (int r = 0; r < 4; ++r)
            cq[(size_t)(m0 + q * 4 + r) * QF] = __float2half(acc[nt][r] * dv[r]);
    }
}

// ---- GEMM2 MFMA: t2q[4][M][32] = fp16( dinv[m] * (h[M,128] @ Wcat)[m] ) ----
__global__ __launch_bounds__(256) void k_gemm2_mfma(const __half* __restrict__ A,
                                                    const __half* __restrict__ Wcfrag,
                                                    const float* __restrict__ dinv,
                                                    __half* __restrict__ C, int M) {
    const int wave = threadIdx.x >> 6;
    const int lane = threadIdx.x & 63;
    const int m0 = blockIdx.x * 64 + wave * 16;
    if (m0 >= M) return;
    const int q = lane >> 4;
    const int arow = m0 + (lane & 15);
    f32x4 acc[8] = {};
#pragma unroll
    for (int ks = 0; ks < 4; ++ks) {
        f16x8 a = *(const f16x8*)(A + (size_t)ks * M * QF + (size_t)arow * QF + q * 8);
        const __half* bbase = Wcfrag + ((size_t)(ks * 8) * 64 + lane) * 8;
#pragma unroll
        for (int nt = 0; nt < 8; ++nt) {
            f16x8 bfrag = *(const f16x8*)(bbase + (size_t)nt * 64 * 8);
            acc[nt] = __builtin_amdgcn_mfma_f32_16x16x32_f16(a, bfrag, acc[nt], 0, 0, 0);
        }
    }
    float dv[4];
#pragma unroll
    for (int r = 0; r < 4; ++r) dv[r] = dinv[m0 + q * 4 + r];
#pragma unroll
    for (int nt = 0; nt < 8; ++nt) {
        int col = nt * 16 + (lane & 15);
        __half* cq = C + (size_t)(col >> 5) * M * QF + (col & 31);
#pragma unroll
        for (int r = 0; r < 4; ++r)
            cq[(size_t)(m0 + q * 4 + r) * QF] = __float2half(acc[nt][r] * dv[r]);
    }
}

// ---- issue one 32-edge chunk's staging loads (2x 16B/lane -> 2KB region) ----
#define ISSUE(C_, LB, SV)                                                      \
    {                                                                          \
        const int eidx_ = gs + (C_) * 32 + row2;                               \
        const __half* gp_ = (eidx_ < ge)                                       \
            ? (tq + (size_t)(SV) * QF + halfo) : (zrow + halfo);               \
        __builtin_amdgcn_global_load_lds(                                      \
            (const __attribute__((address_space(1))) void*)gp_,                \
            (__attribute__((address_space(3))) void*)(LB), 16, 0, 0);          \
        __builtin_amdgcn_global_load_lds(                                      \
            (const __attribute__((address_space(1))) void*)(gp_ + 16),         \
            (__attribute__((address_space(3))) void*)((LB) + 512), 16, 0, 0);  \
    }

// ---- grouped MFMA gather: wave = (16-node group, quarter) ----
// D[r][col] = sum over node r's edges of t[src][feat]; A = membership flags.
template<bool FIRST>
__global__ __launch_bounds__(256) void k_gather_mfma(
        const int* __restrict__ rs, const int* __restrict__ re,
        const int* __restrict__ ssrc, const float* __restrict__ dinv,
        const __half* __restrict__ t, const __half* __restrict__ zrow,
        const float* __restrict__ bA, const float* __restrict__ bB,
        __half* __restrict__ h, float* __restrict__ out,
        int N, int NBWG, int NG) {
    __shared__ __align__(16) __half smem[4][2][1024];   // per wave: 2 x 2KB
    const int wave = threadIdx.x >> 6;
    const int lane = threadIdx.x & 63;
    const int q = blockIdx.x / NBWG;
    const int g = (blockIdx.x - q * NBWG) * 4 + wave;
    if (g >= NG) return;
    const int nb = g << 4;                 // first node of group
    const int row2 = lane >> 1;            // edge slot 0..31 (staging)
    const int halfo = (lane & 1) * 8;      // f16 offset of 16B half-row
    const int col = lane & 15;
    const __half* tq = t + (size_t)q * N * QF;
    __half* buf0 = &smem[wave][0][0];
    __half* buf1 = &smem[wave][1][0];
    const int o0 = rs[nb + col];           // node (=A row) col's edge range
    const int o1 = re[nb + col];
    const int gs = rs[nb];                 // group edge range (contiguous CSR)
    const int ge = re[nb + 15];
    const int nc = (ge - gs + 31) >> 5;
    const int m0 = (lane >> 4) << 2;       // A k->edge permutation base
    const int ebase = gs + m0 - o0;
    const unsigned dd = (unsigned)(o1 - o0);
    f32x4 acc0 = {}, acc1 = {};

    auto ldsrc = [&](int c) -> int {
        int idx = gs + c * 32 + row2;
        idx = idx < ge ? idx : (ge - 1);
        return ssrc[idx];
    };

    int sv_b = 0, sv_c = 0;
    if (nc > 0) {
        const int sv_a = ldsrc(0);
        sv_b = ldsrc(1);
        sv_c = ldsrc(2);
        ISSUE(0, buf0, sv_a);
    }
    for (int c = 0; c < nc; ++c) {
        __half* cur = (c & 1) ? buf1 : buf0;
        if (c + 1 < nc) {
            __half* nxt = (c & 1) ? buf0 : buf1;
            ISSUE(c + 1, nxt, sv_b);
            int sv_n = ldsrc(c + 3);       // clamped; 2-iter latency slack
            asm volatile("s_waitcnt vmcnt(3)" ::: "memory");  // chunk c ready
            sv_b = sv_c; sv_c = sv_n;
        } else {
            asm volatile("s_waitcnt vmcnt(0)" ::: "memory");
        }
        const uint32_t va = lds_addr(cur) + 8u * lane;
        f16x4 r0, r1, r2, r3;
        asm volatile(
            "ds_read_b64_tr_b16 %0, %4 offset:0\n\t"
            "ds_read_b64_tr_b16 %1, %4 offset:512\n\t"
            "ds_read_b64_tr_b16 %2, %4 offset:1024\n\t"
            "ds_read_b64_tr_b16 %3, %4 offset:1536\n\t"
            "s_waitcnt lgkmcnt(0)"
            : "=&v"(r0), "=&v"(r1), "=&v"(r2), "=&v"(r3)
            : "v"(va) : "memory");
        __builtin_amdgcn_sched_barrier(0);
        f16x8 bf0, bf1;
#pragma unroll
        for (int j = 0; j < 4; ++j) {
            bf0[j] = r0[j]; bf0[j + 4] = r1[j];
            bf1[j] = r2[j]; bf1[j + 4] = r3[j];
        }
        // A flags: k = 8g+j maps to edge m0 + (j&3) + 16*(j>>2) within chunk
        const int eb = ebase + c * 32;
        f16x8 af;
#pragma unroll
        for (int j = 0; j < 8; ++j) {
            int m = eb + (j & 3) + ((j >> 2) << 4);
            af[j] = ((unsigned)m < dd) ? (_Float16)1.0f : (_Float16)0.0f;
        }
        acc0 = __builtin_amdgcn_mfma_f32_16x16x32_f16(af, bf0, acc0, 0, 0, 0);
        acc1 = __builtin_amdgcn_mfma_f32_16x16x32_f16(af, bf1, acc1, 0, 0, 0);
    }
    // epilogue: D row = node-in-group = (lane>>4)*4 + reg, col = lane&15
    const int nl0 = (lane >> 4) << 2;
#pragma unroll
    for (int r2 = 0; r2 < 4; ++r2) {
        const int node = nb + nl0 + r2;
        const float di = dinv[node];
        const float s0 = __half2float(tq[(size_t)node * QF + col]);
        const float s1 = __half2float(tq[(size_t)node * QF + 16 + col]);
        float v0 = (acc0[r2] + s0) * di;
        float v1 = (acc1[r2] + s1) * di;
        if constexpr (FIRST) {
            v0 += bA[q * QF + col];
            v1 += bA[q * QF + 16 + col];
            __half* hp = h + (size_t)q * N * QF + (size_t)node * QF;
            hp[col] = __float2half(fmaxf(v0, 0.f));
            hp[16 + col] = __float2half(fmaxf(v1, 0.f));
        } else {
            const float* bp = (q < 2) ? bA : bB;
            const int fb = (q & 1) * QF;
            v0 += bp[fb + col];
            v1 += bp[fb + 16 + col];
            float* op = (q < 2) ? (out + (size_t)node * F2 + fb)
                                : (out + (size_t)N * F2 + (size_t)node * F2 + fb);
            op[col] = v0;
            op[16 + col] = v1;
        }
    }
}

extern "C" void kernel_launch(void* const* d_in, const int* in_sizes, int n_in,
                              void* d_out, int out_size, void* d_ws, size_t ws_size,
                              hipStream_t stream) {
    const float* x   = (const float*)d_in[0];
    const int*   ei  = (const int*)d_in[1];
    const float* W1  = (const float*)d_in[3];
    const float* b1  = (const float*)d_in[4];
    const float* Wmu = (const float*)d_in[5];
    const float* bmu = (const float*)d_in[6];
    const float* Wls = (const float*)d_in[7];
    const float* bls = (const float*)d_in[8];

    const int N = in_sizes[0] / IN_DIM;
    const int E = in_sizes[1] / 2;
    const int* src = ei;
    const int* dst = ei + E;
    float* out = (float*)d_out;
    const int nbuck = cdiv_i(N, BN);   // 391

    // ---- workspace carve (units: 4B slots) ----
    size_t off = 0;
    auto carve = [&](size_t n) { size_t o = off; off += (n + 3) & ~(size_t)3; return o; };
    float* ws = (float*)d_ws;
    float*  dinv   =        ws + carve(N);
    int*    rs     = (int*)(ws + carve(N));
    int*    re     = (int*)(ws + carve(N));
    int*    bcur   = (int*)(ws + carve(512));
    __half* zrow   = (__half*)(ws + carve(16));   // 64B zero row
    int*    ssrc   = (int*)(ws + carve((size_t)nbuck * CAP));
    __half* t16    = (__half*)(ws + carve((size_t)N * F1 / 2));  // [4][N][32]
    __half* h16    = (__half*)(ws + carve((size_t)N * F1 / 2));  // [4][N][32]
    __half* W1frag = (__half*)(ws + carve(8 * 8 * 64 * 8 / 2));
    __half* Wcfrag = (__half*)(ws + carve(4 * 8 * 64 * 8 / 2));
    (void)ws_size;
    // pairs (nbuck*CAP ints = 7.4MB) alias t16 (12.8MB): consumed by
    // k_bucket_build before GEMM1 writes t16.
    int* pairs = (int*)t16;
    __half* t2_16 = t16;   // GEMM2 output reuses t16 (dead after gather1)

    k_prep_frags<<<cdiv_i(8 * 8 * 64 + 4 * 8 * 64, 256), 256, 0, stream>>>(
        W1, Wmu, Wls, W1frag, Wcfrag);

    // CSR build: memset (bcur + zrow, contiguous) + binning + bucket_build
    hipMemsetAsync(bcur, 0, sizeof(int) * 512 + 64, stream);
    k_binning<<<cdiv_i(E, BIN_EDGES), 512, 0, stream>>>(src, dst, bcur, pairs, E);
    k_bucket_build<<<nbuck, 512, 0, stream>>>(pairs, bcur, dinv, rs, re, ssrc, N);

    const int NG = N >> 4;              // 3125 groups of 16 (N % 16 == 0)
    const int NBWG = cdiv_i(NG, 4);     // group-blocks per quarter pass

    // GEMM1 (MFMA): t16 = fp16(dinv * (x @ W1)), quarter-split layout
    k_gemm1_mfma<<<cdiv_i(N, 64), 256, 0, stream>>>(x, W1frag, dinv, t16, N);
    // conv1 aggregate (grouped MFMA-gather) + bias + relu -> h16
    k_gather_mfma<true><<<4 * NBWG, 256, 0, stream>>>(
        rs, re, ssrc, dinv, t16, zrow, b1, b1, h16, out, N, NBWG, NG);
    // GEMM2 (MFMA): t2 = fp16(dinv * (h @ Wcat)), quarter-split
    k_gemm2_mfma<<<cdiv_i(N, 64), 256, 0, stream>>>(h16, Wcfrag, dinv, t2_16, N);
    // conv2 aggregate (grouped MFMA-gather) -> out (mu || logstd), fp32
    k_gather_mfma<false><<<4 * NBWG, 256, 0, stream>>>(
        rs, re, ssrc, dinv, t2_16, zrow, bmu, bls, h16, out, N, NBWG, NG);
}